// Round 8
// baseline (120.285 us; speedup 1.0000x reference)
//
#include <hip/hip_runtime.h>
#include <math.h>

typedef __attribute__((ext_vector_type(8))) short bf16x8;
typedef __attribute__((ext_vector_type(4))) float f32x4;

#define AAM_COS_M 0.9800665778412416f
#define AAM_SIN_M 0.19866933079506122f
#define AAM_TH   (-0.9800665778412416f)
#define AAM_MM    0.03973386615901225f
#define C_CLS 5994

__device__ inline ushort f2bf(float f) {
    unsigned x = __float_as_uint(f);
    return (ushort)((x + 0x7fffu + ((x >> 16) & 1u)) >> 16);
}
__device__ inline float bflo(unsigned u) { return __uint_as_float(u << 16); }
__device__ inline float bfhi(unsigned u) { return __uint_as_float(u & 0xffff0000u); }

// async global->LDS, 16B per lane. LDS dest is wave-uniform base + lane*16.
__device__ __forceinline__ void gload16(const void* g, void* lds) {
    __builtin_amdgcn_global_load_lds(
        (const __attribute__((address_space(1))) unsigned int*)g,
        (__attribute__((address_space(3))) unsigned int*)lds, 16, 0, 0);
}

// ---------------- prep: x->bf16 (4096 blk), Wfc->bf16 (256 blk),
//                  rownorm_w+pad (1536 blk). One dispatch. -------------------
__global__ __launch_bounds__(256) void prep(const float* __restrict__ x,
                                            const float* __restrict__ Wfc,
                                            const float* __restrict__ Waam,
                                            ushort* __restrict__ xb,
                                            ushort* __restrict__ wfcb,
                                            ushort* __restrict__ Wn) {
    const int b = blockIdx.x;
    if (b < 4352) {
        const float* s = (b < 4096) ? x : Wfc;
        ushort* d      = (b < 4096) ? xb : wfcb;
        int i = (b < 4096 ? b : b - 4096) * 256 + threadIdx.x;
        float4 v = ((const float4*)s)[i];
        ushort4 o;
        o.x = f2bf(v.x); o.y = f2bf(v.y); o.z = f2bf(v.z); o.w = f2bf(v.w);
        ((ushort4*)d)[i] = o;
    } else {
        const int wave = threadIdx.x >> 6, lane = threadIdx.x & 63;
        const int row = (b - 4352) * 4 + wave;
        ushort4 o;
        if (row < C_CLS) {
            float4 v = ((const float4*)&Waam[(size_t)row * 256])[lane];
            float ss = v.x * v.x + v.y * v.y + v.z * v.z + v.w * v.w;
#pragma unroll
            for (int m = 32; m >= 1; m >>= 1) ss += __shfl_xor(ss, m, 64);
            float sc = 1.f / fmaxf(sqrtf(ss), 1e-12f);
            o.x = f2bf(v.x * sc); o.y = f2bf(v.y * sc);
            o.z = f2bf(v.z * sc); o.w = f2bf(v.w * sc);
        } else {
            o.x = 0; o.y = 0; o.z = 0; o.w = 0;
        }
        ((ushort4*)&Wn[(size_t)row * 256])[lane] = o;
    }
}

// ---------------- fc GEMM: E = x @ Wfc^T + b (unchanged, proven) ------------
__global__ __launch_bounds__(256) void fc_mfma(const ushort* __restrict__ A,
                                               const ushort* __restrict__ Bm,
                                               const float* __restrict__ bias,
                                               float* __restrict__ C) {
    __shared__ ushort As[64 * 32];
    __shared__ ushort Bs[64 * 32];
    const int tid = threadIdx.x, lane = tid & 63, w = tid >> 6;
    const int wr = w >> 1, wc = w & 1;
    const int lx = lane & 15, lg = lane >> 4;
    const int l4 = lane >> 2, c8 = (lane & 3) << 3;
    const int rb = blockIdx.x * 64, cb = blockIdx.y * 64;

    f32x4 zero = {0.f, 0.f, 0.f, 0.f};
    f32x4 acc[2][2];
#pragma unroll
    for (int i = 0; i < 2; ++i)
#pragma unroll
        for (int j = 0; j < 2; ++j) acc[i][j] = zero;

    for (int k0 = 0; k0 < 1024; k0 += 32) {
        gload16(&A[(size_t)(rb + w * 16 + l4) * 1024 + k0 + c8], &As[w * 512]);
        gload16(&Bm[(size_t)(cb + w * 16 + l4) * 1024 + k0 + c8], &Bs[w * 512]);
        __syncthreads();
        bf16x8 af[2], bv[2];
#pragma unroll
        for (int f = 0; f < 2; ++f) {
            af[f] = *(const bf16x8*)&As[(wr * 32 + f * 16 + lx) * 32 + lg * 8];
            bv[f] = *(const bf16x8*)&Bs[(wc * 32 + f * 16 + lx) * 32 + lg * 8];
        }
#pragma unroll
        for (int i = 0; i < 2; ++i)
#pragma unroll
            for (int j = 0; j < 2; ++j)
                acc[i][j] = __builtin_amdgcn_mfma_f32_16x16x32_bf16(af[i], bv[j], acc[i][j], 0, 0, 0);
        __syncthreads();
    }
#pragma unroll
    for (int j = 0; j < 2; ++j) {
        int col = cb + wc * 32 + j * 16 + lx;
        float bb = bias[col];
#pragma unroll
        for (int i = 0; i < 2; ++i) {
            int row0 = rb + wr * 32 + i * 16 + lg * 4;
#pragma unroll
            for (int r = 0; r < 4; ++r)
                C[(size_t)(row0 + r) * 256 + col] = acc[i][j][r] + bb;
        }
    }
}

// ---------------- row L2-normalize E (fp32) -> bf16 -------------------------
__global__ __launch_bounds__(256) void rownorm_e(const float* __restrict__ E,
                                                 ushort* __restrict__ En) {
    const int wave = threadIdx.x >> 6, lane = threadIdx.x & 63;
    const int row = blockIdx.x * 4 + wave;
    float4 v = ((const float4*)&E[(size_t)row * 256])[lane];
    float ss = v.x * v.x + v.y * v.y + v.z * v.z + v.w * v.w;
#pragma unroll
    for (int m = 32; m >= 1; m >>= 1) ss += __shfl_xor(ss, m, 64);
    float sc = 1.f / fmaxf(sqrtf(ss), 1e-12f);
    ushort4 o;
    o.x = f2bf(v.x * sc); o.y = f2bf(v.y * sc); o.z = f2bf(v.z * sc); o.w = f2bf(v.w * sc);
    ((ushort4*)&En[(size_t)row * 256])[lane] = o;
}

// ---------------- cosine GEMM + exp-sum partials + label-cos capture --------
// M=4096, N=6144(pad), K=256. 128x128 tiles, BK=64, double-buffered 2-phase.
// Grid (32,16)=512 blocks, 4 waves 2x2, each 64x64 (4x4 frags).
// Fixed softmax stabilizer: logits = 30*cos <= 30, so m = 30 a priori.
// The label column's exact MFMA cosine is captured to cosl[row] here.
__global__ __launch_bounds__(256, 2) void aam_mfma(const ushort* __restrict__ A,
                                                   const ushort* __restrict__ Bm,
                                                   const int* __restrict__ lab,
                                                   float* __restrict__ ps,
                                                   float* __restrict__ cosl) {
    __shared__ ushort As[2][128 * 64];
    __shared__ ushort Bs[2][128 * 64];
    const int tid = threadIdx.x, lane = tid & 63, w = tid >> 6;
    const int wr = w >> 1, wc = w & 1;
    const int lx = lane & 15, lg = lane >> 4;
    const int rb = blockIdx.x * 128;
    const int split = blockIdx.y;

    // staging: lane covers row (lane>>3) in an 8-row group; 16B slot (lane&7).
    // T2 both-sides swizzle: global col pre-XORed, read applies same XOR.
    const int lrow = lane >> 3;
    const int gcol = ((lane & 7) ^ lrow) * 8;

    // my 16 output rows' labels (row = rb + wr*64 + (idx>>2)*16 + lg*4 + (idx&3))
    int labs[16];
#pragma unroll
    for (int idx = 0; idx < 16; ++idx)
        labs[idx] = lab[rb + wr * 64 + (idx >> 2) * 16 + lg * 4 + (idx & 3)];

    float srun[16];
#pragma unroll
    for (int idx = 0; idx < 16; ++idx) srun[idx] = 0.f;

    f32x4 zero = {0.f, 0.f, 0.f, 0.f};
    f32x4 acc[4][4];
#pragma unroll
    for (int i = 0; i < 4; ++i)
#pragma unroll
        for (int j = 0; j < 4; ++j) acc[i][j] = zero;

#define AAM_STAGE(buf, g) do {                                                  \
    int t_ = (g) >> 2, k0_ = ((g) & 3) * 64;                                    \
    int cb_ = split * 384 + t_ * 128;                                           \
    _Pragma("unroll")                                                           \
    for (int s_ = 0; s_ < 4; ++s_) {                                            \
        int r0_ = w * 32 + s_ * 8;                                              \
        gload16(&A[(size_t)(rb + r0_ + lrow) * 256 + k0_ + gcol],               \
                &As[buf][r0_ * 64]);                                            \
        gload16(&Bm[(size_t)(cb_ + r0_ + lrow) * 256 + k0_ + gcol],             \
                &Bs[buf][r0_ * 64]);                                            \
    } } while (0)

    int cur = 0;
    AAM_STAGE(0, 0);
    __syncthreads();            // buf0 ready

    for (int g = 0; g < 12; ++g) {
        if (g < 11) AAM_STAGE(cur ^ 1, g + 1);   // prefetch next step
#pragma unroll
        for (int kk = 0; kk < 2; ++kk) {
            bf16x8 af[4], bv[4];
#pragma unroll
            for (int f = 0; f < 4; ++f) {
                int ra = wr * 64 + f * 16 + lx;
                int ca = (lg + kk * 4) ^ (lx & 7);   // ra&7 == lx&7
                af[f] = *(const bf16x8*)&As[cur][ra * 64 + ca * 8];
                int rq = wc * 64 + f * 16 + lx;
                bv[f] = *(const bf16x8*)&Bs[cur][rq * 64 + ca * 8];
            }
#pragma unroll
            for (int i = 0; i < 4; ++i)
#pragma unroll
                for (int j = 0; j < 4; ++j)
                    acc[i][j] = __builtin_amdgcn_mfma_f32_16x16x32_bf16(af[i], bv[j], acc[i][j], 0, 0, 0);
        }
        if ((g & 3) == 3) {     // end of a 128-col tile: fold + label capture
            int cb_ = split * 384 + (g >> 2) * 128;
#pragma unroll
            for (int j = 0; j < 4; ++j) {
                int c = cb_ + wc * 64 + j * 16 + lx;
                if (c < C_CLS) {
#pragma unroll
                    for (int i = 0; i < 4; ++i)
#pragma unroll
                        for (int r = 0; r < 4; ++r) {
                            int idx = i * 4 + r;
                            float cosv = acc[i][j][r];
                            srun[idx] += __expf(30.f * cosv - 30.f);
                            if (c == labs[idx])
                                cosl[rb + wr * 64 + i * 16 + lg * 4 + r] = cosv;
                        }
                }
            }
#pragma unroll
            for (int i = 0; i < 4; ++i)
#pragma unroll
                for (int j = 0; j < 4; ++j) acc[i][j] = zero;
        }
        __syncthreads();
        cur ^= 1;
    }
#undef AAM_STAGE

    // sum srun over the 16 lx-lanes sharing each row; store transposed
#pragma unroll
    for (int idx = 0; idx < 16; ++idx) {
#pragma unroll
        for (int msk = 1; msk < 16; msk <<= 1)
            srun[idx] += __shfl_xor(srun[idx], msk, 64);
        if (lx == 0) {
            int row = rb + wr * 64 + (idx >> 2) * 16 + lg * 4 + (idx & 3);
            ps[(size_t)row * 32 + split * 2 + wc] = srun[idx];
        }
    }
}

// ---------------- stage 1: thread-per-row nll, 16 block partials ------------
__global__ __launch_bounds__(256) void reduce_nll(const float* __restrict__ ps,
                                                  const float* __restrict__ cosl,
                                                  float* __restrict__ partial) {
    __shared__ float red[4];
    const int row = blockIdx.x * 256 + threadIdx.x;
    const int wave = threadIdx.x >> 6, lane = threadIdx.x & 63;
    float s = 0.f;
#pragma unroll
    for (int q = 0; q < 8; ++q) {
        float4 v = ((const float4*)&ps[(size_t)row * 32])[q];
        s += v.x + v.y + v.z + v.w;
    }
    float cv = cosl[row];
    float sine = sqrtf(fmaxf(1.f - cv * cv, 0.f));
    float phi = cv * AAM_COS_M - sine * AAM_SIN_M;
    phi = ((cv - AAM_TH) > 0.f) ? phi : (cv - AAM_MM);
    // s counted the label col with exp(30cv-30); swap for exp(30phi-30)
    float denom = s - __expf(30.f * cv - 30.f) + __expf(30.f * phi - 30.f);
    float nll = 30.f + logf(denom) - 30.f * phi;
#pragma unroll
    for (int m = 32; m >= 1; m >>= 1) nll += __shfl_xor(nll, m, 64);
    if (lane == 0) red[wave] = nll;
    __syncthreads();
    if (threadIdx.x == 0)
        partial[blockIdx.x] = red[0] + red[1] + red[2] + red[3];
}

// ---------------- stage 2: sum 16 partials -> mean --------------------------
__global__ __launch_bounds__(64) void final_reduce(const float* __restrict__ partial,
                                                   float* __restrict__ out) {
    const int lane = threadIdx.x;
    float v = (lane < 16) ? partial[lane] : 0.f;
#pragma unroll
    for (int m = 32; m >= 1; m >>= 1) v += __shfl_xor(v, m, 64);
    if (lane == 0) out[0] = v * (1.f / 4096.f);
}

extern "C" void kernel_launch(void* const* d_in, const int* in_sizes, int n_in,
                              void* d_out, int out_size, void* d_ws, size_t ws_size,
                              hipStream_t stream) {
    const float* x    = (const float*)d_in[0];
    const int*   lab  = (const int*)d_in[1];
    const float* Wfc  = (const float*)d_in[2];
    const float* bfc  = (const float*)d_in[3];
    const float* Waam = (const float*)d_in[4];
    float* out = (float*)d_out;

    char* ws = (char*)d_ws;
    ushort* xb   = (ushort*)(ws);                 // [0, 8388608)
    ushort* Wfcb = (ushort*)(ws + 8388608);       // [8388608, 8912896)
    float*  E    = (float*) (ws + 8912896);       // [8912896, 13107200)
    ushort* En   = (ushort*)(ws);                 // [0, 2097152) overlay dead xb
    ushort* Wn   = (ushort*)(ws + 13107200);      // [13107200, 16252928)
    float*  ps   = (float*) (ws + 16252928);      // 512 KB, layout [row*32+part]
    float*  cosl = (float*) (ws + 16777216);      // 16 KB
    float*  part = (float*) (ws + 16793600);      // 64 B

    prep<<<5888, 256, 0, stream>>>(x, Wfc, Waam, xb, Wfcb, Wn);
    fc_mfma<<<dim3(64, 4), 256, 0, stream>>>(xb, Wfcb, bfc, E);
    rownorm_e<<<1024, 256, 0, stream>>>(E, En);
    aam_mfma<<<dim3(32, 16), 256, 0, stream>>>(En, Wn, lab, ps, cosl);
    reduce_nll<<<16, 256, 0, stream>>>(ps, cosl, part);
    final_reduce<<<1, 64, 0, stream>>>(part, out);
}